// Round 12
// baseline (119.322 us; speedup 1.0000x reference)
//
#include <hip/hip_runtime.h>
#include <hip/hip_bf16.h>

// Problem constants (B,N,E,H,D) = (2,2048,1024,16,64)
#define B_ 2
#define N_ 2048
#define E_ 1024
#define H_ 16
#define D_ 64
#define M_ 4096      // B*N
#define HD_ 1024     // H*D
#define NT_ 3072     // 3*H*D

using f32x4  = __attribute__((ext_vector_type(4))) float;
using f32x16 = __attribute__((ext_vector_type(16))) float;
using bf16x8 = __attribute__((ext_vector_type(8))) short;

static __device__ __forceinline__ unsigned short f2bf(float f) {
  union { float f; unsigned u; } v; v.f = f;
  unsigned r = v.u + 0x7FFF + ((v.u >> 16) & 1);   // RNE
  return (unsigned short)(r >> 16);
}
static __device__ __forceinline__ float bf2f(short s) {
  union { unsigned u; float f; } v; v.u = ((unsigned)(unsigned short)s) << 16; return v.f;
}

// async global->LDS, 16B per lane. LDS dest = wave-uniform base + lane*16.
static __device__ __forceinline__ void gld16(const void* g, void* l) {
  __builtin_amdgcn_global_load_lds(
      (const __attribute__((address_space(1))) unsigned int*)g,
      (__attribute__((address_space(3))) unsigned int*)l, 16, 0, 0);
}

static __device__ __forceinline__ unsigned cvtpk(float lo, float hi) {
  unsigned r;
  asm("v_cvt_pk_bf16_f32 %0, %1, %2" : "=v"(r) : "v"(lo), "v"(hi));
  return r;
}
static __device__ __forceinline__ void pl32swap(unsigned& a, unsigned& b) {
  asm("v_permlane32_swap_b32 %0, %1" : "+v"(a), "+v"(b));
}

// gemm LDS sub-chunk swizzle (16B units within a 64B row)
static __device__ __forceinline__ int gswz(int row) {
  return ((row >> 1) & 3) ^ ((row >> 3) & 1);
}

// ---------------- conversion kernels ----------------

__global__ void k_cvt_x(const float* __restrict__ x, unsigned short* __restrict__ xb) {
  int t = blockIdx.x * 256 + threadIdx.x;          // one float4 per thread
  float4 v = reinterpret_cast<const float4*>(x)[t];
  ushort4 o;
  o.x = f2bf(v.x); o.y = f2bf(v.y); o.z = f2bf(v.z); o.w = f2bf(v.w);
  reinterpret_cast<ushort4*>(xb)[t] = o;
}

// Wqkv rows interleaved (h, d, kind): rin = h*192 + d*3 + kind.
// Output row r = kind*1024 + h*64 + d; Q rows pre-scaled by (1/8)*log2(e).
__global__ void k_cvt_wqkv(const float* __restrict__ w, const float* __restrict__ bsrc,
                           unsigned short* __restrict__ wb, float* __restrict__ br) {
  int t = blockIdx.x * 256 + threadIdx.x;
  int r = t >> 8;
  int c = (t & 255) * 4;
  int kind = r >> 10, hd = r & 1023;
  int h = hd >> 6, d = hd & 63;
  int rin = h * 192 + d * 3 + kind;
  float s = (kind == 0) ? 0.125f * 1.4426950408889634f : 1.0f;
  float4 v = *reinterpret_cast<const float4*>(w + (size_t)rin * E_ + c);
  ushort4 o;
  o.x = f2bf(v.x * s); o.y = f2bf(v.y * s); o.z = f2bf(v.z * s); o.w = f2bf(v.w * s);
  *reinterpret_cast<ushort4*>(wb + (size_t)r * E_ + c) = o;
  if (c == 0) br[r] = bsrc[rin] * s;
}

__global__ void k_cvt_wout(const float* __restrict__ w, unsigned short* __restrict__ wb) {
  int t = blockIdx.x * 256 + threadIdx.x;
  int r = t >> 8;
  int c = (t & 255) * 4;
  float4 v = *reinterpret_cast<const float4*>(w + (size_t)r * HD_ + c);
  ushort4 o;
  o.x = f2bf(v.x); o.y = f2bf(v.y); o.z = f2bf(v.z); o.w = f2bf(v.w);
  *reinterpret_cast<ushort4*>(wb + (size_t)r * HD_ + c) = o;
}

// ---------------- GEMM: R9 main loop + VECTORIZED epilogues ----------------
// Epilogue rework (the R12 change): scalar 2B stores (64/thread) replaced by
//  - kind<2 (Q/K): LDS bounce (reuses staging LDS post-loop) -> 8x 16B stores
//  - kind==2 (V): 4 consecutive tokens @ same d pack into one 8B store (16/thread)
//  - EPI==1: f32 LDS bounce -> 8x float4 stores
template <int EPI, int BM>
__global__ __launch_bounds__(256, 2) void k_gemm(
    const unsigned short* __restrict__ A,   // [M][K] bf16
    const unsigned short* __restrict__ W,   // [Nt][K] bf16
    const float* __restrict__ bias,         // [Nt]
    unsigned short* __restrict__ Qo, unsigned short* __restrict__ Ko,
    unsigned short* __restrict__ Vo, float* __restrict__ Fo,
    int M, int Nt, int K)
{
  constexpr int APT = (BM == 128) ? 2 : 1;
  constexpr int LPI = APT + 2;
  constexpr int NF  = (BM == 128) ? 4 : 2;
  constexpr int ASZ = 3 * BM * 32;           // elems
  constexpr int MAIN_B = (ASZ + 3 * 128 * 32) * 2;
  constexpr int EPI_B  = (EPI == 0) ? 128 * 136 * 2 : 64 * 132 * 4;
  constexpr int SMB = MAIN_B > EPI_B ? MAIN_B : EPI_B;
  __shared__ alignas(16) char smem[SMB];
  unsigned short* AsBase = (unsigned short*)smem;
  unsigned short* BsBase = AsBase + ASZ;

  const int t = threadIdx.x;
  const int w = t >> 6, l = t & 63, lg = l >> 4, lr = l & 15;
  const int wrow0 = (BM == 128) ? (w >> 1) * 64 : 0;
  const int wcol0 = (BM == 128) ? (w & 1) * 64 : w * 32;
  const int row0 = blockIdx.x * BM, col0 = blockIdx.y * 128;
  const int NT = K >> 5;

  f32x4 acc[4][NF] = {};

  auto stage = [&](int b, int k0) {
#pragma unroll
    for (int c = 0; c < APT; ++c) {
      int ci = w * APT + c;
      int row = ci * 16 + (l >> 2);
      int sub = (l & 3) ^ gswz(row);
      gld16(A + (size_t)(row0 + row) * K + k0 + sub * 8, AsBase + b * BM * 32 + ci * 512);
    }
#pragma unroll
    for (int c = 0; c < 2; ++c) {
      int ci = w * 2 + c;
      int row = ci * 16 + (l >> 2);
      int sub = (l & 3) ^ gswz(row);
      gld16(W + (size_t)(col0 + row) * K + k0 + sub * 8, BsBase + b * 128 * 32 + ci * 512);
    }
  };

  stage(0, 0);
  stage(1, 32);

  for (int kt = 0; kt < NT; ++kt) {
    const int ib = kt % 3;
    if (kt + 2 < NT) stage((kt + 2) % 3, (kt + 2) * 32);
    const int na = NT - 1 - kt;
    if (na >= 2) {
      if constexpr (LPI == 4) asm volatile("s_waitcnt vmcnt(8)" ::: "memory");
      else                    asm volatile("s_waitcnt vmcnt(6)" ::: "memory");
    } else if (na == 1) {
      if constexpr (LPI == 4) asm volatile("s_waitcnt vmcnt(4)" ::: "memory");
      else                    asm volatile("s_waitcnt vmcnt(3)" ::: "memory");
    } else {
      asm volatile("s_waitcnt vmcnt(0)" ::: "memory");
    }
    asm volatile("s_barrier" ::: "memory");

    bf16x8 af[4], bf[NF];
#pragma unroll
    for (int m = 0; m < 4; ++m) {
      int row = wrow0 + m * 16 + lr;
      af[m] = *reinterpret_cast<const bf16x8*>(
          &AsBase[ib * BM * 32 + row * 32 + ((lg ^ gswz(row)) * 8)]);
    }
#pragma unroll
    for (int n = 0; n < NF; ++n) {
      int row = wcol0 + n * 16 + lr;
      bf[n] = *reinterpret_cast<const bf16x8*>(
          &BsBase[ib * 128 * 32 + row * 32 + ((lg ^ gswz(row)) * 8)]);
    }
    __builtin_amdgcn_s_setprio(1);
#pragma unroll
    for (int m = 0; m < 4; ++m)
#pragma unroll
      for (int n = 0; n < NF; ++n)
        acc[m][n] = __builtin_amdgcn_mfma_f32_16x16x32_bf16(af[m], bf[n], acc[m][n], 0, 0, 0);
    __builtin_amdgcn_s_setprio(0);

    asm volatile("s_barrier" ::: "memory");
  }

  // ---------------- vectorized epilogues ----------------
  if (EPI == 0) {
    const int kind = col0 >> 10;             // uniform per block (128 | 1024)
    if (kind < 2) {
      // LDS bounce: [128][136] bf16, then 8x bf16x8 coalesced stores
      unsigned short* eb = (unsigned short*)smem;
#pragma unroll
      for (int m = 0; m < 4; ++m)
#pragma unroll
        for (int n = 0; n < NF; ++n) {
          int c = wcol0 + n * 16 + lr;
          float bb = bias[col0 + c];
#pragma unroll
          for (int rr = 0; rr < 4; ++rr)
            eb[(wrow0 + m * 16 + lg * 4 + rr) * 136 + c] = f2bf(acc[m][n][rr] + bb);
        }
      __syncthreads();
      unsigned short* outp = kind ? Ko : Qo;
      int h0 = (col0 & 1023) >> 6;
      int row = t >> 1, cs = (t & 1) * 64;
      int ro = row0 + row;
      int bi = ro >> 11, ni = ro & 2047;
#pragma unroll
      for (int j = 0; j < 8; ++j) {
        int c = cs + j * 8;
        int h = h0 + (c >> 6), d = c & 63;
        bf16x8 v = *reinterpret_cast<const bf16x8*>(&eb[row * 136 + c]);
        *reinterpret_cast<bf16x8*>(
            &outp[((size_t)(bi * H_ + h) * N_ + ni) * D_ + d]) = v;
      }
    } else {
      // V: 4 consecutive tokens @ same d -> one 8B packed store each
#pragma unroll
      for (int m = 0; m < 4; ++m)
#pragma unroll
        for (int n = 0; n < NF; ++n) {
          int hd = (col0 + wcol0 + n * 16 + lr) & 1023;
          int h = hd >> 6, d = hd & 63;
          float bb = bias[col0 + wcol0 + n * 16 + lr];
          int ro = row0 + wrow0 + m * 16 + lg * 4;
          int bi = ro >> 11, ni = ro & 2047;
          ushort4 pk;
          pk.x = f2bf(acc[m][n][0] + bb);
          pk.y = f2bf(acc[m][n][1] + bb);
          pk.z = f2bf(acc[m][n][2] + bb);
          pk.w = f2bf(acc[m][n][3] + bb);
          *reinterpret_cast<ushort4*>(
              &Vo[((size_t)(bi * H_ + h) * D_ + d) * N_ + ni]) = pk;
        }
    }
  } else {
    // f32 LDS bounce: [64][132], then 8x float4 stores
    float* ef = (float*)smem;
#pragma unroll
    for (int m = 0; m < 4; ++m)
#pragma unroll
      for (int n = 0; n < NF; ++n) {
        int c = wcol0 + n * 16 + lr;
        float bb = bias[col0 + c];
#pragma unroll
        for (int rr = 0; rr < 4; ++rr)
          ef[(m * 16 + lg * 4 + rr) * 132 + c] = acc[m][n][rr] + bb;
      }
    __syncthreads();
    int row = t >> 2, cs = (t & 3) * 32;
#pragma unroll
    for (int j = 0; j < 8; ++j) {
      float4 v = *reinterpret_cast<const float4*>(&ef[row * 132 + cs + j * 4]);
      *reinterpret_cast<float4*>(
          &Fo[(size_t)(row0 + row) * HD_ + col0 + cs + j * 4]) = v;
    }
  }
}

// ---------------- flash attention (R11 2-state pipeline + vectorized epilogue) ----------------
__global__ __launch_bounds__(256, 3) void k_attn(
    const unsigned short* __restrict__ Q,
    const unsigned short* __restrict__ Kg,
    const unsigned short* __restrict__ Vg,
    unsigned short* __restrict__ O,
    unsigned short* __restrict__ Pp,    // [bh][16][128][64] bf16 partial O~
    float* __restrict__ Pml)            // [bh][16][128]  l
{
  static const int u_qt[24] = {15,15,14,13,12,11,10, 9,   8, 7,14, 6,13, 5,12, 4,   8, 0, 9, 1,10, 2,11, 3};
  static const int u_t0[24] = { 0,16, 0, 0, 0, 0, 0, 0,   0, 0,16, 0,16, 0,16, 0,  16, 0,16, 0,16, 0,16, 0};
  static const int u_ps[24] = {14,15,12,10, 8, 6, 4, 2,   0,-1,13,-1,11,-1, 9,-1,   1,-1, 3,-1, 5,-1, 7,-1};

  __shared__ alignas(16) unsigned short Ks[3][64 * 64];
  __shared__ alignas(16) unsigned short Vs[3][64 * 64];

  const int t = threadIdx.x;
  const int w = t >> 6, l = t & 63;
  const int lq = l & 31;
  const int hi = l >> 5;
  const int bh = blockIdx.x & 31;
  const int u  = blockIdx.x >> 5;
  const int qt = u_qt[u], t0 = u_t0[u], ps = u_ps[u];
  const int q0 = qt * 128;
  const int r0w = q0 + w * 32;
  const int rtop = r0w + 31;
  const bool splitc0 = (ps >= 0) && (t0 == 0);
  const int tendW = splitc0 ? 16 : ((rtop >> 6) + 1);
  const int tendB = splitc0 ? 16 : (((q0 + 127) >> 6) + 1);

  const unsigned short* Qb = Q  + (size_t)bh * (N_ * D_);
  const unsigned short* Kb = Kg + (size_t)bh * (N_ * D_);
  const unsigned short* Vb = Vg + (size_t)bh * (N_ * D_);   // [d][n]

  const int pr  = l >> 3;
  const int pswz = ((l & 7) ^ pr) * 8;
  const unsigned short* KsrcB = Kb + pr * D_ + pswz;
  const unsigned short* VsrcB = Vb + pr * N_ + pswz;

  bf16x8 qf[4];
#pragma unroll
  for (int ks = 0; ks < 4; ++ks)
    qf[ks] = *reinterpret_cast<const bf16x8*>(
        Qb + (size_t)(r0w + lq) * D_ + ks * 16 + hi * 8);

  f32x16 oacc[2] = {};
  float lrun = 0.f;

  auto stage = [&](int b, int kt_) {
    const int kv = kt_ * 64;
#pragma unroll
    for (int c = 0; c < 2; ++c) {
      int cb = w * 2 + c;
      gld16(KsrcB + kv * D_ + cb * 512, (unsigned short*)&Ks[b][0] + cb * 512);
      gld16(VsrcB + kv + cb * 8 * N_,   (unsigned short*)&Vs[b][0] + cb * 512);
    }
  };

  auto read_kf = [&](int b, bf16x8 kf[2][4]) {
#pragma unroll
    for (int ct = 0; ct < 2; ++ct)
#pragma unroll
      for (int ks = 0; ks < 4; ++ks) {
        int row = ct * 32 + lq;
        kf[ct][ks] = *reinterpret_cast<const bf16x8*>(
            &Ks[b][row * 64 + (((ks * 2 + hi) ^ (lq & 7)) * 8)]);
      }
  };

  stage(0, t0);
  stage(1, t0 + 1);
  asm volatile("s_waitcnt vmcnt(4)" ::: "memory");
  __syncthreads();

  f32x16 scur[2];
  {
    bf16x8 kf[2][4];
    read_kf(0, kf);
#pragma unroll
    for (int ct = 0; ct < 2; ++ct) {
      f32x16 z = {};
#pragma unroll
      for (int ks = 0; ks < 4; ++ks)
        z = __builtin_amdgcn_mfma_f32_32x32x16_bf16(kf[ct][ks], qf[ks], z, 0, 0, 0);
      scur[ct] = z;
    }
  }

  for (int kt = t0; kt < tendB; ++kt) {
    const int ib  = (kt - t0) % 3;
    const int ib1 = (kt - t0 + 1) % 3;
    if (kt + 2 < tendB) {
      stage((kt - t0 + 2) % 3, kt + 2);
      asm volatile("s_waitcnt vmcnt(4)" ::: "memory");
    } else {
      asm volatile("s_waitcnt vmcnt(0)" ::: "memory");
    }
    asm volatile("s_barrier" ::: "memory");

    bf16x8 kf[2][4];
    read_kf(ib1, kf);
    f32x16 snext[2];
#pragma unroll
    for (int ct = 0; ct < 2; ++ct) {
      f32x16 z = {};
#pragma unroll
      for (int ks = 0; ks < 4; ++ks)
        z = __builtin_amdgcn_mfma_f32_32x32x16_bf16(kf[ct][ks], qf[ks], z, 0, 0, 0);
      snext[ct] = z;
    }

    if (kt < tendW) {
      const int kv0 = kt * 64;
      if (kv0 + 63 > r0w) {
        int qrow = r0w + lq;
#pragma unroll
        for (int ct = 0; ct < 2; ++ct)
#pragma unroll
          for (int r = 0; r < 16; ++r) {
            int kv = kv0 + ct * 32 + (r & 3) + 8 * (r >> 2) + 4 * hi;
            if (kv > qrow) scur[ct][r] = -1e30f;
          }
      }

      float s16[16];
#pragma unroll
      for (int r = 0; r < 16; ++r) {
        float p0 = exp2f(scur[0][r]);
        float p1 = exp2f(scur[1][r]);
        scur[0][r] = p0; scur[1][r] = p1;
        s16[r] = p0 + p1;
      }
#pragma unroll
      for (int st = 8; st >= 1; st >>= 1)
#pragma unroll
        for (int r = 0; r < 8; ++r)
          if (r < st) s16[r] += s16[r + st];
      lrun += s16[0] + __shfl_xor(s16[0], 32);

      bf16x8 paf[4];
#pragma unroll
      for (int ct = 0; ct < 2; ++ct) {
        unsigned u0 = cvtpk(scur[ct][0],  scur[ct][1]);
        unsigned u1 = cvtpk(scur[ct][2],  scur[ct][3]);
        unsigned u2 = cvtpk(scur[ct][4],  scur[ct][5]);
        unsigned u3 = cvtpk(scur[ct][6],  scur[ct][7]);
        unsigned u4 = cvtpk(scur[ct][8],  scur[ct][9]);
        unsigned u5 = cvtpk(scur[ct][10], scur[ct][11]);
        unsigned u6 = cvtpk(scur[ct][12], scur[ct][13]);
        unsigned u7 = cvtpk(scur[ct][14], scur[ct][15]);
        pl32swap(u0, u2); pl32swap(u1, u3);
        pl32swap(u4, u6); pl32swap(u5, u7);
        union { unsigned uu[4]; bf16x8 v; } c0, c1;
        c0.uu[0] = u0; c0.uu[1] = u1; c0.uu[2] = u2; c0.uu[3] = u3;
        c1.uu[0] = u4; c1.uu[1] = u5; c1.uu[2] = u6; c1.uu[3] = u7;
        paf[ct * 2]     = c0.v;
        paf[ct * 2 + 1] = c1.v;
      }

      bf16x8 vf[2][4];
#pragma unroll
      for (int dt = 0; dt < 2; ++dt)
#pragma unroll
        for (int j = 0; j < 4; ++j) {
          int row = dt * 32 + lq;
          vf[dt][j] = *reinterpret_cast<const bf16x8*>(
              &Vs[ib][row * 64 + (((j * 2 + hi) ^ (lq & 7)) * 8)]);
        }
      __builtin_amdgcn_s_setprio(1);
#pragma unroll
      for (int dt = 0; dt < 2; ++dt)
#pragma unroll
        for (int j = 0; j < 4; ++j)
          oacc[dt] = __builtin_amdgcn_mfma_f32_32x32x16_bf16(paf[j], vf[dt][j], oacc[dt], 0, 0, 0);
      __builtin_amdgcn_s_setprio(0);
    }

    scur[0] = snext[0];
    scur[1] = snext[1];
    asm volatile("s_barrier" ::: "memory");
  }

  // ---- vectorized epilogue: bounce through Ks LDS (free after final barrier) ----
  int bi = bh >> 4, h = bh & 15;
  float scale = (ps < 0) ? (1.0f / lrun) : 1.0f;
  float iv[16];
#pragma unroll
  for (int r = 0; r < 16; ++r)
    iv[r] = __shfl(scale, (r & 3) + 8 * (r >> 2) + 4 * hi);
  unsigned short* eb = (unsigned short*)&Ks[0][0];   // [128][72]
#pragma unroll
  for (int dt = 0; dt < 2; ++dt)
#pragma unroll
    for (int r = 0; r < 16; ++r) {
      int rloc = w * 32 + (r & 3) + 8 * (r >> 2) + 4 * hi;
      eb[rloc * 72 + dt * 32 + lq] = f2bf(oacc[dt][r] * iv[r]);
    }
  if (ps >= 0 && l < 32)
    Pml[(size_t)(bh * 16 + ps) * 128 + w * 32 + l] = lrun;
  __syncthreads();
  int rl = t >> 1, dsg = (t & 1) * 32;
  if (ps < 0) {
    int qr = q0 + rl;
    unsigned short* op = O + ((size_t)(bi * N_ + qr) * H_ + h) * D_ + dsg;
#pragma unroll
    for (int j = 0; j < 4; ++j)
      *reinterpret_cast<bf16x8*>(op + j * 8) =
          *reinterpret_cast<const bf16x8*>(&eb[rl * 72 + dsg + j * 8]);
  } else {
    unsigned short* pb = Pp + (size_t)(bh * 16 + ps) * (128 * 64) + rl * 64 + dsg;
#pragma unroll
    for (int j = 0; j < 4; ++j)
      *reinterpret_cast<bf16x8*>(pb + j * 8) =
          *reinterpret_cast<const bf16x8*>(&eb[rl * 72 + dsg + j * 8]);
  }
}

// ---------------- merge the two kv-chunk partials for q0>=1024 tiles ----------------
__global__ void k_merge(const unsigned short* __restrict__ Pp,
                        const float* __restrict__ Pml,
                        unsigned short* __restrict__ O) {
  int t = blockIdx.x * 256 + threadIdx.x;   // 262144 threads
  int dseg = t & 7;
  int rloc = (t >> 3) & 127;
  int qt8 = (t >> 10) & 7;
  int bh  = t >> 13;
  size_t b0 = (size_t)(bh * 16 + qt8 * 2) * 128 + rloc;
  size_t b1 = b0 + 128;
  bf16x8 o0 = *reinterpret_cast<const bf16x8*>(Pp + b0 * 64 + dseg * 8);
  bf16x8 o1 = *reinterpret_cast<const bf16x8*>(Pp + b1 * 64 + dseg * 8);
  float l0 = Pml[b0], l1 = Pml[b1];
  float inv = 1.0f / (l0 + l1);
  int n = (qt8 + 8) * 128 + rloc;
  int bi = bh >> 4, h = bh & 15;
  unsigned short* op = O + ((size_t)(bi * N_ + n) * H_ + h) * D_ + dseg * 8;
  bf16x8 res;
#pragma unroll
  for (int j = 0; j < 8; ++j)
    res[j] = (short)f2bf((bf2f(o0[j]) + bf2f(o1[j])) * inv);
  *reinterpret_cast<bf16x8*>(op) = res;
}

// ---------------- launch ----------------

extern "C" void kernel_launch(void* const* d_in, const int* in_sizes, int n_in,
                              void* d_out, int out_size, void* d_ws, size_t ws_size,
                              hipStream_t stream) {
  const float* x    = (const float*)d_in[0];
  const float* Wqkv = (const float*)d_in[1];
  const float* bqkv = (const float*)d_in[2];
  const float* Wout = (const float*)d_in[3];
  const float* bout = (const float*)d_in[4];
  float* out = (float*)d_out;

  char* ws = (char*)d_ws;
  unsigned short* xb  = (unsigned short*)ws; ws += (size_t)M_ * E_ * 2;       // 8 MB
  unsigned short* wqb = (unsigned short*)ws; ws += (size_t)NT_ * E_ * 2;      // 6 MB
  float*          bqr = (float*)ws;          ws += 16384;                     // 16 KB
  unsigned short* wob = (unsigned short*)ws; ws += (size_t)E_ * HD_ * 2;      // 2 MB
  unsigned short* Qb  = (unsigned short*)ws; ws += (size_t)M_ * D_ * H_ * 2;  // 8 MB
  unsigned short* Kb  = (unsigned short*)ws; ws += (size_t)M_ * D_ * H_ * 2;  // 8 MB
  unsigned short* Vb  = (unsigned short*)ws; ws += (size_t)M_ * D_ * H_ * 2;  // 8 MB
  unsigned short* ao  = (unsigned short*)ws; ws += (size_t)M_ * HD_ * 2;      // 8 MB

  // attention partials ALIAS xb/wqb (dead after gemm0)
  unsigned short* Pp  = xb;            // 8 MB
  float*          Pml = (float*)wqb;   // 256 KB

  k_cvt_x<<<(M_ * E_) / 4 / 256, 256, 0, stream>>>(x, xb);
  k_cvt_wqkv<<<NT_, 256, 0, stream>>>(Wqkv, bqkv, wqb, bqr);
  k_cvt_wout<<<E_, 256, 0, stream>>>(Wout, wob);

  k_gemm<0, 128><<<dim3(M_ / 128, NT_ / 128), 256, 0, stream>>>(
      xb, wqb, bqr, Qb, Kb, Vb, nullptr, M_, NT_, E_);

  k_attn<<<768, 256, 0, stream>>>(Qb, Kb, Vb, ao, Pp, Pml);
  k_merge<<<1024, 256, 0, stream>>>(Pp, Pml, ao);

  k_gemm<1, 64><<<dim3(M_ / 64, HD_ / 128), 256, 0, stream>>>(
      ao, wob, bout, nullptr, nullptr, nullptr, out, M_, HD_, E_);
}